// Round 14
// baseline (1600.685 us; speedup 1.0000x reference)
//
#include <hip/hip_runtime.h>
#include <hip/hip_bf16.h>

// GraphProcessor: S=16,B=64,C=128,H=W=11,P=121, 3 iterations.
// Transposed [sb][p][128ch] bf16 storage; MFMA everywhere; deep fusion.
// This round: conv3 on mfma_f32_32x32x16_bf16, 64oc x 32p wave tiles (2x B-reuse).
#define S_   16
#define B_   64
#define SBn  1024
#define C_   128
#define P_   121
#define CP_  15488
static const long NEl = 15859712L; // SBn*CP_

typedef __hip_bfloat16 bf16t;
typedef __attribute__((ext_vector_type(8))) short bf16x8;
typedef __attribute__((ext_vector_type(4))) float f32x4;
typedef __attribute__((ext_vector_type(16))) float f32x16;
typedef __attribute__((ext_vector_type(4))) unsigned short us4;

__device__ __forceinline__ float ldb(const bf16t* p){ return __bfloat162float(*p); }
__device__ __forceinline__ float b2f(unsigned short u){ unsigned x=((unsigned)u)<<16; float f; __builtin_memcpy(&f,&x,4); return f; }
__device__ __forceinline__ unsigned short f2bu(float v){ __hip_bfloat16 b=__float2bfloat16(v); unsigned short u; __builtin_memcpy(&u,&b,2); return u; }
__device__ __forceinline__ float ldin(const void* s, long i, int f){
    return f ? ((const float*)s)[i] : b2f(((const unsigned short*)s)[i]);
}

// ---------- dtype detect: flag=1 if inputs are f32, 0 if bf16 ----------
__global__ void detect_kernel(const unsigned short* __restrict__ x, int* __restrict__ flag){
    if(blockIdx.x==0 && threadIdx.x==0){
        int crazy=0;
        for(int i=0;i<512;i++){
            unsigned e=(x[i]>>7)&0xFF;
            if(e!=0 && (e<64 || e>191)) crazy++;
        }
        *flag=(crazy>40)?1:0;
    }
}

// ---------- raw input -> f32 ----------
__global__ void cvt_kernel(float* __restrict__ dst, const void* __restrict__ src, long n, const int* __restrict__ flag){
    long i=(long)blockIdx.x*blockDim.x+threadIdx.x;
    long st=(long)gridDim.x*blockDim.x;
    int f=*flag;
    for(;i<n;i+=st) dst[i]=ldin(src,i,f);
}

// ---------- x [sb][c][p] -> hT [sb][p][c] bf16, LDS-tiled (coalesced both sides) ----------
__global__ __launch_bounds__(256) void cvtT_kernel(bf16t* __restrict__ hT, const void* __restrict__ x, const int* __restrict__ flag){
    __shared__ bf16t tl[CP_];   // [c][p]
    int sb=blockIdx.x, t=threadIdx.x; int f=*flag;
    for(int i=t;i<CP_;i+=256)
        tl[i]=__float2bfloat16(ldin(x,(long)sb*CP_+i,f));
    __syncthreads();
    bf16t* ho=hT+(size_t)sb*CP_;
    for(int j=t;j<CP_;j+=256){
        int p=j>>7, c=j&127;
        ho[j]=tl[c*P_+p];
    }
}

// ---------- fold w_lin @ w_msg[:, :C] into W2 (f32), edge bias into b2l/b2r ----------
__global__ __launch_bounds__(128) void prep_msg_kernel(float* __restrict__ W2, float* __restrict__ b2l, float* __restrict__ b2r,
        const void* __restrict__ wlin, const void* __restrict__ wmsg, const void* __restrict__ bmsg, const int* __restrict__ flag){
    int d=blockIdx.x, c=threadIdx.x; int f=*flag;
    float acc=0.f;
    for(int o2=0;o2<C_;o2++) acc += ldin(wlin,(long)d*C_+o2,f)*ldin(wmsg,(long)o2*(C_+1)+c,f);
    W2[d*C_+c]=acc;
    if(c<2){
        float e=(c==0)?1.f:-1.f; float a=0.f;
        for(int o2=0;o2<C_;o2++) a += ldin(wlin,(long)d*C_+o2,f)*(ldin(bmsg,o2,f)+e*ldin(wmsg,(long)o2*(C_+1)+C_,f));
        if(c==0) b2l[d]=a; else b2r[d]=a;
    }
}

// ---------- 1x1 weight [oc][128ic] -> tiled bf16 [icb(4)][oc(128)][32] ----------
template<int RAW>
__global__ void prep_w1t(bf16t* __restrict__ dst, const void* __restrict__ src, const int* __restrict__ flag){
    int idx=blockIdx.x*blockDim.x+threadIdx.x;
    if(idx>=16384) return;
    int r=idx&31, oc=(idx>>5)&127, icb=idx>>12;
    float v = RAW? ldin(src,(long)oc*C_+icb*32+r,*flag) : ((const float*)src)[(long)oc*C_+icb*32+r];
    dst[idx]=__float2bfloat16(v);
}

// ---------- 3x3 weight [oc][256ic][3][3] -> bf16 [tap][k16(16)][oc][16] for 32x32x16 ----------
__global__ void prep_w3t32(bf16t* __restrict__ dst, const void* __restrict__ src, const int* __restrict__ flag, int OC){
    int idx=blockIdx.x*blockDim.x+threadIdx.x;
    int tot=OC*2304;
    if(idx>=tot) return;
    int r=idx&15; int rest=idx>>4; int oc=rest%OC; int g2=rest/OC; int k16=g2&15, tap=g2>>4;
    float v=ldin(src,((long)(oc*256+k16*16+r))*9+tap,*flag);
    dst[idx]=__float2bfloat16(v);
}

// ---------- gamma/beta [c][p] -> transposed f32 [p][c] ----------
__global__ void prep_gbt(float* __restrict__ gamT, float* __restrict__ betT,
                         const void* __restrict__ gam, const void* __restrict__ bet, const int* __restrict__ flag){
    int idx=blockIdx.x*blockDim.x+threadIdx.x;
    if(idx>=CP_) return;
    int c=idx/P_, p=idx-c*P_; int f=*flag;
    gamT[p*C_+c]=ldin(gam,idx,f);
    betT[p*C_+c]=ldin(bet,idx,f);
}

// ---------- w_gate [c][k] -> transposed f32 [k][c]; b_gate -> f32 ----------
__global__ void prep_wgt(float* __restrict__ wgT, float* __restrict__ bg2,
                         const void* __restrict__ wg, const void* __restrict__ bg, const int* __restrict__ flag){
    int idx=blockIdx.x*blockDim.x+threadIdx.x;
    int f=*flag;
    if(idx<16384){ int k=idx>>7, c=idx&127; wgT[idx]=ldin(wg,(long)c*C_+k,f); }
    if(idx<128) bg2[idx]=ldin(bg,idx,f);
}

// ---------- 128x128x128 GEMM tile, 8 waves (2 ocr x 4 pcr), B from registers ----------
__device__ __forceinline__ void gemm24r(f32x4 (&acc)[4][2],
    const bf16t* __restrict__ Wt, const bf16x8 (&hreg)[4][2],
    int ocr,int l15,int kg)
{
    #pragma unroll
    for(int i=0;i<4;i++){
        #pragma unroll
        for(int j=0;j<2;j++) acc[i][j]=(f32x4){0.f,0.f,0.f,0.f};
    }
    #pragma unroll
    for(int kc=0;kc<4;kc++){
        bf16x8 a[4];
        #pragma unroll
        for(int mt=0;mt<4;mt++) a[mt]=*(const bf16x8*)(Wt+((size_t)(kc*C_+ocr*64+mt*16+l15))*32+kg*8);
        #pragma unroll
        for(int mt=0;mt<4;mt++){
            #pragma unroll
            for(int nt=0;nt<2;nt++)
                acc[mt][nt]=__builtin_amdgcn_mfma_f32_16x16x32_bf16(a[mt],hreg[kc][nt],acc[mt][nt],0,0,0);
        }
    }
}

// ---------- one message-direction phase: yy=W2@h_shift; m=softmax(h yy^T) yy; gate; res += (1-w)*m*g ----------
__device__ __forceinline__ void msg_phase(
    f32x4 (&res)[8], const bf16t* __restrict__ hT, int sb, int shift,
    const bf16t* __restrict__ W2T, const float* __restrict__ b2e,
    const float* __restrict__ wgT, const float* __restrict__ bgf, float w1m,
    const bf16x8 (&areg)[4],
    bf16t* LA, bf16t* LB, float* fl,
    int t,int w,int l15,int kg,int ocr,int pcr)
{
    __syncthreads();   // previous phase's LDS reads complete
    const bf16t* hsp=hT+(size_t)(sb+shift)*CP_;
    bf16x8 hregS[4][2];
    #pragma unroll
    for(int kc=0;kc<4;kc++){
        #pragma unroll
        for(int nt=0;nt<2;nt++)
            hregS[kc][nt]=*(const bf16x8*)(hsp+(size_t)(pcr*32+nt*16+l15)*C_+kc*32+kg*8);
    }
    f32x4 acc[4][2];
    gemm24r(acc,W2T,hregS,ocr,l15,kg);
    #pragma unroll
    for(int mt=0;mt<4;mt++){
        int oc0=ocr*64+mt*16+kg*4;
        #pragma unroll
        for(int nt=0;nt<2;nt++){
            int p=pcr*32+nt*16+l15;
            us4 pk;
            #pragma unroll
            for(int r=0;r<4;r++){
                float v=acc[mt][nt][r]+b2e[oc0+r];
                pk[r]=f2bu(v);
                LB[(oc0+r)*136+p]=__float2bfloat16(p<P_? v : 0.f);
            }
            *(us4*)(LA+p*136+oc0)=pk;
        }
    }
    __syncthreads();
    int m0=w*16;
    f32x4 s[8];
    #pragma unroll
    for(int nt=0;nt<8;nt++) s[nt]=(f32x4){0.f,0.f,0.f,0.f};
    #pragma unroll
    for(int kc=0;kc<4;kc++){
        #pragma unroll
        for(int nt=0;nt<8;nt++){
            bf16x8 b=*(const bf16x8*)(LA+(size_t)(nt*16+l15)*136+kc*32+kg*8);
            s[nt]=__builtin_amdgcn_mfma_f32_16x16x32_bf16(areg[kc],b,s[nt],0,0,0);
        }
    }
    if(l15>=9){
        #pragma unroll
        for(int r=0;r<4;r++) s[7][r]=-3.0e38f;
    }
    #pragma unroll
    for(int r=0;r<4;r++){
        float mx=s[0][r];
        #pragma unroll
        for(int nt=1;nt<8;nt++) mx=fmaxf(mx,s[nt][r]);
        #pragma unroll
        for(int o=1;o<16;o<<=1) mx=fmaxf(mx,__shfl_xor(mx,o));
        float sm=0.f;
        #pragma unroll
        for(int nt=0;nt<8;nt++){ float e=__expf(s[nt][r]-mx); s[nt][r]=e; sm+=e; }
        #pragma unroll
        for(int o=1;o<16;o<<=1) sm+=__shfl_xor(sm,o);
        float rs=1.f/sm;
        #pragma unroll
        for(int nt=0;nt<8;nt++) s[nt][r]*=rs;
    }
    __syncthreads();   // yyT reads done
    #pragma unroll
    for(int r=0;r<4;r++){
        int pr=m0+kg*4+r;
        #pragma unroll
        for(int nt=0;nt<8;nt++) LA[pr*136+nt*16+l15]=__float2bfloat16(s[nt][r]);
    }
    __syncthreads();
    f32x4 o[8];
    #pragma unroll
    for(int nt=0;nt<8;nt++) o[nt]=(f32x4){0.f,0.f,0.f,0.f};
    #pragma unroll
    for(int jc=0;jc<4;jc++){
        bf16x8 a=*(const bf16x8*)(LB+(size_t)(m0+l15)*136+jc*32+kg*8);
        #pragma unroll
        for(int nt=0;nt<8;nt++){
            bf16x8 b=*(const bf16x8*)(LA+(size_t)(nt*16+l15)*136+jc*32+kg*8);
            o[nt]=__builtin_amdgcn_mfma_f32_16x16x32_bf16(a,b,o[nt],0,0,0);
        }
    }
    int c0=m0+kg*4;
    #pragma unroll
    for(int r=0;r<4;r++){
        float sm=0.f;
        #pragma unroll
        for(int nt=0;nt<8;nt++){ float v=o[nt][r]; if(nt==7&&l15>8) v=0.f; sm+=v; }
        sm+=__shfl_xor(sm,1); sm+=__shfl_xor(sm,2); sm+=__shfl_xor(sm,4); sm+=__shfl_xor(sm,8);
        if(l15==0) fl[c0+r]=sm*(1.f/121.f);
    }
    __syncthreads();
    if(t<C_){
        float a=bgf[t];
        #pragma unroll 8
        for(int k=0;k<C_;k++) a+=wgT[k*C_+t]*fl[k];
        fl[C_+t]=1.f/(1.f+__expf(-a));
    }
    __syncthreads();
    float gg[4];
    #pragma unroll
    for(int r=0;r<4;r++) gg[r]=fl[C_+c0+r];
    #pragma unroll
    for(int nt=0;nt<8;nt++){
        #pragma unroll
        for(int r=0;r<4;r++) res[nt][r]+=w1m*o[nt][r]*gg[r];
    }
}

// ---------- fused intra + left-msg + right-msg per (s,b), 512 threads ----------
__global__ __launch_bounds__(512) void attn_all(
    bf16t* __restrict__ comb, const bf16t* __restrict__ hT,
    const bf16t* __restrict__ WqT, const bf16t* __restrict__ WkT, const bf16t* __restrict__ WvT,
    const float* __restrict__ bq, const float* __restrict__ bk, const float* __restrict__ bv,
    const bf16t* __restrict__ W2T, const float* __restrict__ b2l, const float* __restrict__ b2r,
    const float* __restrict__ wgT, const float* __restrict__ bgf,
    const float* __restrict__ alphap, const float* __restrict__ wp)
{
    __shared__ bf16t LA[128*136];
    __shared__ bf16t LB[128*136];
    __shared__ float fl[256];
    int sb=blockIdx.x, t=threadIdx.x, lane=t&63, w=t>>6;
    int l15=lane&15, kg=lane>>4;
    const bf16t* hp=hT+(size_t)sb*CP_;
    int ocr=w>>2, pcr=w&3;
    int m0=w*16;
    bf16x8 hreg[4][2];
    #pragma unroll
    for(int kc=0;kc<4;kc++){
        #pragma unroll
        for(int nt=0;nt<2;nt++)
            hreg[kc][nt]=*(const bf16x8*)(hp+(size_t)(pcr*32+nt*16+l15)*C_+kc*32+kg*8);
    }
    bf16x8 areg[4];
    #pragma unroll
    for(int kc=0;kc<4;kc++)
        areg[kc]=*(const bf16x8*)(hp+(size_t)(m0+l15)*C_+kc*32+kg*8);

    f32x4 acc[4][2];
    // q -> LA [p][c]
    gemm24r(acc,WqT,hreg,ocr,l15,kg);
    #pragma unroll
    for(int mt=0;mt<4;mt++){
        int oc0=ocr*64+mt*16+kg*4;
        #pragma unroll
        for(int nt=0;nt<2;nt++){
            int p=pcr*32+nt*16+l15;
            us4 pk;
            #pragma unroll
            for(int r=0;r<4;r++) pk[r]=f2bu(acc[mt][nt][r]+bq[oc0+r]);
            *(us4*)(LA+p*136+oc0)=pk;
        }
    }
    // k -> LB [p][c]
    gemm24r(acc,WkT,hreg,ocr,l15,kg);
    #pragma unroll
    for(int mt=0;mt<4;mt++){
        int oc0=ocr*64+mt*16+kg*4;
        #pragma unroll
        for(int nt=0;nt<2;nt++){
            int p=pcr*32+nt*16+l15;
            us4 pk;
            #pragma unroll
            for(int r=0;r<4;r++) pk[r]=f2bu(acc[mt][nt][r]+bk[oc0+r]);
            *(us4*)(LB+p*136+oc0)=pk;
        }
    }
    __syncthreads();
    // QK^T
    f32x4 s[8];
    #pragma unroll
    for(int nt=0;nt<8;nt++) s[nt]=(f32x4){0.f,0.f,0.f,0.f};
    #pragma unroll
    for(int kc=0;kc<4;kc++){
        bf16x8 a=*(const bf16x8*)(LA+(size_t)(m0+l15)*136+kc*32+kg*8);
        #pragma unroll
        for(int nt=0;nt<8;nt++){
            bf16x8 b=*(const bf16x8*)(LB+(size_t)(nt*16+l15)*136+kc*32+kg*8);
            s[nt]=__builtin_amdgcn_mfma_f32_16x16x32_bf16(a,b,s[nt],0,0,0);
        }
    }
    const float scale=0.08838834764831845f;
    #pragma unroll
    for(int nt=0;nt<8;nt++){
        #pragma unroll
        for(int r=0;r<4;r++) s[nt][r]*=scale;
    }
    if(l15>=9){
        #pragma unroll
        for(int r=0;r<4;r++) s[7][r]=-3.0e38f;
    }
    #pragma unroll
    for(int r=0;r<4;r++){
        float mx=s[0][r];
        #pragma unroll
        for(int nt=1;nt<8;nt++) mx=fmaxf(mx,s[nt][r]);
        #pragma unroll
        for(int o=1;o<16;o<<=1) mx=fmaxf(mx,__shfl_xor(mx,o));
        float sm=0.f;
        #pragma unroll
        for(int nt=0;nt<8;nt++){ float e=__expf(s[nt][r]-mx); s[nt][r]=e; sm+=e; }
        #pragma unroll
        for(int o=1;o<16;o<<=1) sm+=__shfl_xor(sm,o);
        float rs=1.f/sm;
        #pragma unroll
        for(int nt=0;nt<8;nt++) s[nt][r]*=rs;
    }
    __syncthreads();   // q/k reads done
    // v -> LA natural [c][p]; P -> LB [p][j]
    gemm24r(acc,WvT,hreg,ocr,l15,kg);
    #pragma unroll
    for(int mt=0;mt<4;mt++){
        int oc0=ocr*64+mt*16+kg*4;
        #pragma unroll
        for(int nt=0;nt<2;nt++){
            int p=pcr*32+nt*16+l15;
            #pragma unroll
            for(int r=0;r<4;r++)
                LA[(oc0+r)*136+p]=__float2bfloat16(p<P_? acc[mt][nt][r]+bv[oc0+r] : 0.f);
        }
    }
    #pragma unroll
    for(int r=0;r<4;r++){
        int pr=m0+kg*4+r;
        #pragma unroll
        for(int nt=0;nt<8;nt++) LB[pr*136+nt*16+l15]=__float2bfloat16(s[nt][r]);
    }
    __syncthreads();
    // PV
    f32x4 res[8];
    #pragma unroll
    for(int nt=0;nt<8;nt++) res[nt]=(f32x4){0.f,0.f,0.f,0.f};
    #pragma unroll
    for(int jc=0;jc<4;jc++){
        bf16x8 a=*(const bf16x8*)(LA+(size_t)(m0+l15)*136+jc*32+kg*8);
        #pragma unroll
        for(int nt=0;nt<8;nt++){
            bf16x8 b=*(const bf16x8*)(LB+(size_t)(nt*16+l15)*136+jc*32+kg*8);
            res[nt]=__builtin_amdgcn_mfma_f32_16x16x32_bf16(a,b,res[nt],0,0,0);
        }
    }
    float al=*alphap, wv=*wp, w1m=1.f-wv;
    int c0=m0+kg*4;
    #pragma unroll
    for(int nt=0;nt<8;nt++){
        int p=nt*16+l15;
        int pc=(p<P_)?p:(P_-1);
        us4 hv=*(const us4*)(hp+(size_t)pc*C_+c0);
        #pragma unroll
        for(int r=0;r<4;r++) res[nt][r]=wv*(al*res[nt][r]+b2f(hv[r]));
    }
    if(sb>=B_)
        msg_phase(res,hT,sb,-B_,W2T,b2l,wgT,bgf,w1m,areg,LA,LB,fl,t,w,l15,kg,ocr,pcr);
    if(sb<SBn-B_)
        msg_phase(res,hT,sb, B_,W2T,b2r,wgT,bgf,w1m,areg,LA,LB,fl,t,w,l15,kg,ocr,pcr);
    __syncthreads();
    unsigned short* tl=(unsigned short*)LA;
    #pragma unroll
    for(int nt=0;nt<8;nt++){
        int p=nt*16+l15;
        if(p>=P_) continue;
        us4 pk;
        #pragma unroll
        for(int r=0;r<4;r++) pk[r]=f2bu(res[nt][r]);
        *(us4*)(tl+p*C_+c0)=pk;
    }
    __syncthreads();
    bf16t* ob=comb+(size_t)sb*CP_;
    for(int j=t;j<1936;j+=512)
        *(bf16x8*)(ob+j*8)=*(const bf16x8*)(tl+j*8);
}

// ---------- 32x32x16 conv3 macros: A prefetch (8 frags/tap), B 4 reads/tap reused by 2 oc-tiles ----------
#define LOADA32(bidx, gk) { \
    _Pragma("unroll") \
    for(int ot=0;ot<2;ot++){ \
        _Pragma("unroll") \
        for(int kk=0;kk<4;kk++) \
            abuf[bidx][ot][kk]=*(const bf16x8*)(Wt+(((size_t)(gk)+kk)*OC+aoc0+ot*32)*16+ah8); } }
#define TAP32(lbase, bidx, d) { \
    bf16x8 br[4]; \
    _Pragma("unroll") \
    for(int kk=0;kk<4;kk++) br[kk]=*(const bf16x8*)((lbase)+bpix0+(d)+kk*16); \
    __builtin_amdgcn_s_setprio(1); \
    _Pragma("unroll") \
    for(int kk=0;kk<4;kk++){ \
        accA=__builtin_amdgcn_mfma_f32_32x32x16_bf16(abuf[bidx][0][kk],br[kk],accA,0,0,0); \
        accB=__builtin_amdgcn_mfma_f32_32x32x16_bf16(abuf[bidx][1][kk],br[kk],accB,0,0,0); \
    } \
    __builtin_amdgcn_s_setprio(0); }

// staging (512 thr, 968 chunks of 8 bf16, 2 per thread)
#define SLOAD32(stg) { \
    const bf16t* ssrc=(((stg)<2)? in0T:in1T)+(size_t)sb*CP_+((stg)&1)*64; \
    sreg[0]=*(const bf16x8*)(ssrc+(size_t)(t>>3)*C_+(t&7)*8); \
    if(sv1) sreg[1]=*(const bf16x8*)(ssrc+(size_t)sp1*C_+(t&7)*8); }
#define SWRITE32(lbase) { \
    *(bf16x8*)((lbase)+spix0*72+(t&7)*8)=sreg[0]; \
    if(sv1) *(bf16x8*)((lbase)+spix1*72+(t&7)*8)=sreg[1]; }

// ---------- zr conv: grid (SBn,2); y=0 -> Z (sigmoid), y=1 -> RH (sigmoid*h) ----------
__global__ __launch_bounds__(512) void conv3_zr(
    bf16t* __restrict__ o0, bf16t* __restrict__ o1,
    const bf16t* __restrict__ in0T, const bf16t* __restrict__ in1T,
    const bf16t* __restrict__ Wt, const float* __restrict__ bias,
    const bf16t* __restrict__ hTb)
{
    constexpr int OC=256;
    __shared__ bf16t lin[2*12176];
    int sb=blockIdx.x, ocb=(int)blockIdx.y*128;
    int t=threadIdx.x, lane=t&63, w=t>>6;           // w 0..7
    int ocr=w>>2, pcr=w&3;                          // 2 oc64-groups x 4 p32-groups
    int c31=lane&31, h=lane>>5;
    int p0=pcr*32+c31;
    bool pv0=(p0<P_);
    int pc0=pv0?p0:(P_-1);
    int bpix0=((pc0/11)*13+(pc0%11))*72+h*8;
    f32x16 accA,accB;
    #pragma unroll
    for(int j=0;j<16;j++){ accA[j]=0.f; accB[j]=0.f; }
    int aoc0=ocb+ocr*64+c31, ah8=h*8;
    bf16x8 abuf[2][2][4];
    bf16x8 sreg[2];
    bool sv1=((t+512)<968);
    int sp0=t>>3, sp1=(t+512)>>3;
    if(sp1>120) sp1=120;
    int spix0=(sp0/11+1)*13+(sp0%11)+1;
    int spix1=(sp1/11+1)*13+(sp1%11)+1;
    LOADA32(0,0);
    SLOAD32(0);
    {
        bf16x8 z;
        #pragma unroll
        for(int e=0;e<8;e++) z[e]=0;
        for(int i=t;i<768;i+=512){
            int half=i>=384; int i2=i-half*384;
            int bi=i2>>3, cc=(i2&7)*8;
            int pix;
            if(bi<13) pix=bi;
            else if(bi<26) pix=156+(bi-13);
            else { int j2=bi-26; pix=(1+(j2>>1))*13+((j2&1)?12:0); }
            *(bf16x8*)(lin+half*12176+pix*72+cc)=z;
        }
    }
    SWRITE32(lin);
    __syncthreads();
    #pragma unroll
    for(int st=0; st<4; ++st){
        if(st<3) SLOAD32(st+1);
        bf16t* lbase=lin+(st&1)*12176;
        #pragma unroll
        for(int tap=0;tap<9;tap++){
            int g=st*9+tap;
            if(g<35){
                int g1=g+1, st1=g1/9, tap1=g1-st1*9;
                LOADA32(g1&1, tap1*16+st1*4);
            }
            int d=((tap/3)*13+(tap%3))*72;
            TAP32(lbase, g&1, d);
        }
        if(st<3){ SWRITE32(lin+((st+1)&1)*12176); }
        __syncthreads();
    }
    // epilogue: stage [p][128c] in lin, coalesced copy out
    unsigned short* tl=(unsigned short*)lin;
    if(pv0){
        if(ocb==0){
            #pragma unroll
            for(int a=0;a<4;a++){
                int ocA=ocr*64+8*a+4*h, ocB=ocA+32;
                us4 pkA,pkB;
                #pragma unroll
                for(int r=0;r<4;r++){
                    float vA=accA[4*a+r]+bias[ocA+r];
                    float vB=accB[4*a+r]+bias[ocB+r];
                    pkA[r]=f2bu(1.f/(1.f+__expf(-vA)));
                    pkB[r]=f2bu(1.f/(1.f+__expf(-vB)));
                }
                *(us4*)(tl+p0*C_+ocA)=pkA;
                *(us4*)(tl+p0*C_+ocB)=pkB;
            }
        }else{
            #pragma unroll
            for(int a=0;a<4;a++){
                int ocA=ocr*64+8*a+4*h, ocB=ocA+32;
                size_t tbA=(size_t)sb*CP_+(size_t)p0*C_+ocA;
                size_t tbB=(size_t)sb*CP_+(size_t)p0*C_+ocB;
                us4 hvA=*(const us4*)(hTb+tbA);
                us4 hvB=*(const us4*)(hTb+tbB);
                us4 pkA,pkB;
                #pragma unroll
                for(int r=0;r<4;r++){
                    float vA=accA[4*a+r]+bias[128+ocA+r];
                    float vB=accB[4*a+r]+bias[128+ocB+r];
                    float sA=1.f/(1.f+__expf(-vA));
                    float sB=1.f/(1.f+__expf(-vB));
                    pkA[r]=f2bu(sA*b2f(hvA[r]));
                    pkB[r]=f2bu(sB*b2f(hvB[r]));
                }
                *(us4*)(tl+p0*C_+ocA)=pkA;
                *(us4*)(tl+p0*C_+ocB)=pkB;
            }
        }
    }
    __syncthreads();
    {
        bf16t* ob=(ocb==0? o0 : o1)+(size_t)sb*CP_;
        for(int j=t;j<1936;j+=512)
            *(bf16x8*)(ob+j*8)=*(const bf16x8*)(tl+j*8);
    }
}

// ---------- hhat conv + GRU-combine + LayerNorm: 512 threads, 32x32x16 ----------
__global__ __launch_bounds__(512) void conv3_hh(
    bf16t* __restrict__ o0,
    const bf16t* __restrict__ in0T, const bf16t* __restrict__ in1T,
    const bf16t* __restrict__ Wt, const float* __restrict__ bias,
    const bf16t* __restrict__ zT, const bf16t* __restrict__ hTb,
    const float* __restrict__ gamT, const float* __restrict__ betT)
{
    constexpr int OC=128;
    __shared__ bf16t lin[2*12176];
    __shared__ float red[16];
    int sb=blockIdx.x;
    int t=threadIdx.x, lane=t&63, w=t>>6;           // w 0..7
    int ocr=w>>2, pcr=w&3;                          // 2 oc64 x 4 p32
    int c31=lane&31, h=lane>>5;
    int p0=pcr*32+c31;
    bool pv0=(p0<P_);
    int pc0=pv0?p0:(P_-1);
    int bpix0=((pc0/11)*13+(pc0%11))*72+h*8;
    f32x16 accA,accB;
    #pragma unroll
    for(int j=0;j<16;j++){ accA[j]=0.f; accB[j]=0.f; }
    int aoc0=ocr*64+c31, ah8=h*8;
    bf16x8 abuf[2][2][4];
    bf16x8 sreg[2];
    bool sv1=((t+512)<968);
    int sp0=t>>3, sp1=(t+512)>>3;
    if(sp1>120) sp1=120;
    int spix0=(sp0/11+1)*13+(sp0%11)+1;
    int spix1=(sp1/11+1)*13+(sp1%11)+1;
    LOADA32(0,0);
    SLOAD32(0);
    {
        bf16x8 z;
        #pragma unroll
        for(int e=0;e<8;e++) z[e]=0;
        for(int i=t;i<768;i+=512){
            int half=i>=384; int i2=i-half*384;
            int bi=i2>>3, cc=(i2&7)*8;
            int pix;
            if(bi<13) pix=bi;
            else if(bi<26) pix=156+(bi-13);
            else { int j2=bi-26; pix=(1+(j2>>1))*13+((j2&1)?12:0); }
            *(bf16x8*)(lin+half*12176+pix*72+cc)=z;
        }
    }
    SWRITE32(lin);
    __syncthreads();
    #pragma unroll
    for(int st=0; st<4; ++st){
        if(st<3) SLOAD32(st+1);
        bf16t* lbase=lin+(st&1)*12176;
        #pragma unroll
        for(int tap=0;tap<9;tap++){
            int g=st*9+tap;
            if(g<35){
                int g1=g+1, st1=g1/9, tap1=g1-st1*9;
                LOADA32(g1&1, tap1*16+st1*4);
            }
            int d=((tap/3)*13+(tap%3))*72;
            TAP32(lbase, g&1, d);
        }
        if(st<3){ SWRITE32(lin+((st+1)&1)*12176); }
        __syncthreads();
    }
    // GRU combine -> NH in LDS [p][c], LayerNorm, write new hT
    float ls=0.f, ls2=0.f;
    if(pv0){
        #pragma unroll
        for(int a=0;a<4;a++){
            int ocA=ocr*64+8*a+4*h, ocB=ocA+32;
            size_t tbA=(size_t)sb*CP_+(size_t)p0*C_+ocA;
            size_t tbB=(size_t)sb*CP_+(size_t)p0*C_+ocB;
            us4 hvA=*(const us4*)(hTb+tbA); us4 zvA=*(const us4*)(zT+tbA);
            us4 hvB=*(const us4*)(hTb+tbB); us4 zvB=*(const us4*)(zT+tbB);
            us4 pkA,pkB;
            #pragma unroll
            for(int r=0;r<4;r++){
                float aA=accA[4*a+r]+bias[ocA+r];
                float aB=accB[4*a+r]+bias[ocB+r];
                float htA=tanhf(aA), htB=tanhf(aB);
                float zA=b2f(zvA[r]), hA=b2f(hvA[r]);
                float zB=b2f(zvB[r]), hB=b2f(hvB[r]);
                unsigned short uA=f2bu((1.f-zA)*hA+zA*htA+hA);
                unsigned short uB=f2bu((1.f-zB)*hB+zB*htB+hB);
                pkA[r]=uA; pkB[r]=uB;
                float nA=b2f(uA), nB=b2f(uB);
                ls+=nA+nB; ls2+=nA*nA+nB*nB;
            }
            *(us4*)((unsigned short*)lin+p0*C_+ocA)=pkA;
            *(us4*)((unsigned short*)lin+p0*C_+ocB)=pkB;
        }
    }
    #pragma unroll
    for(int o=32;o;o>>=1){ ls+=__shfl_xor(ls,o); ls2+=__shfl_xor(ls2,o); }
    if(lane==0){ red[w]=ls; red[8+w]=ls2; }
    __syncthreads();
    float Sx=0.f,Sx2=0.f;
    #pragma unroll
    for(int i=0;i<8;i++){ Sx+=red[i]; Sx2+=red[8+i]; }
    float mu=Sx*(1.f/(float)CP_);
    float var=Sx2*(1.f/(float)CP_)-mu*mu;
    float rstd=rsqrtf(var+1e-5f);
    bf16t* ho=o0+(size_t)sb*CP_;
    const unsigned short* tl=(const unsigned short*)lin;
    for(int j=t;j<1936;j+=512){
        int base=j*8;
        bf16x8 ovec;
        #pragma unroll
        for(int e=0;e<8;e++){
            float v=(b2f(tl[base+e])-mu)*rstd*gamT[base+e]+betT[base+e];
            ovec[e]=(short)f2bu(v);
        }
        *(bf16x8*)(ho+base)=ovec;
    }
}

// ---------- final: hT [p][c] -> natural [c][p] output ----------
__global__ __launch_bounds__(256) void finalT_kernel(void* __restrict__ fout, const bf16t* __restrict__ hT, const int* __restrict__ flag){
    __shared__ bf16t tl[CP_];
    int sb=blockIdx.x, t=threadIdx.x, f=*flag;
    for(int i=t;i<CP_;i+=256) tl[i]=hT[(size_t)sb*CP_+i];
    __syncthreads();
    for(int i=t;i<CP_;i+=256){
        int c=i/P_, p=i-c*P_;
        float v=ldb(tl+p*C_+c);
        size_t oi=(size_t)sb*CP_+i;
        if(f) ((float*)fout)[oi]=v;
        else  ((bf16t*)fout)[oi]=__float2bfloat16(v);
    }
}

extern "C" void kernel_launch(void* const* d_in, const int* in_sizes, int n_in,
                              void* d_out, int out_size, void* d_ws, size_t ws_size,
                              hipStream_t stream) {
    (void)in_sizes; (void)n_in; (void)out_size;
    char* base=(char*)d_ws;
    size_t off=0;
    auto alloc=[&](size_t bytes){ void* p=base+off; off+=(bytes+255)&~(size_t)255; return p; };
    bf16t* b1=(bf16t*)alloc((size_t)NEl*2+8192);          // hT
    bf16t* b2=(bf16t*)alloc((size_t)NEl*2+8192);          // comb
    bf16t* b3=(bf16t*)alloc((size_t)NEl*2+8192);          // RH
    bf16t* b4=(bf16t*)d_out;                              // Z / final
    bf16t* wqT=(bf16t*)alloc(16384*2);
    bf16t* wkT=(bf16t*)alloc(16384*2);
    bf16t* wvT=(bf16t*)alloc(16384*2);
    bf16t* w2T=(bf16t*)alloc(16384*2);
    bf16t* wzrT=(bf16t*)alloc((size_t)589824*2);
    bf16t* whT =(bf16t*)alloc((size_t)294912*2);
    float* W2f=(float*)alloc(16384*4);
    float* b2l=(float*)alloc(128*4); float* b2r=(float*)alloc(128*4);
    float* bqf=(float*)alloc(128*4); float* bkf=(float*)alloc(128*4); float* bvf=(float*)alloc(128*4);
    float* bzrf=(float*)alloc(256*4); float* bhf=(float*)alloc(128*4);
    float* gamT=(float*)alloc(15488*4); float* betT=(float*)alloc(15488*4);
    float* wgTf=(float*)alloc(16384*4); float* bgf2=(float*)alloc(128*4);
    float* alphaf=(float*)alloc(4); float* weightf=(float*)alloc(4);
    int* flag=(int*)alloc(4);
    if(ws_size<off) return;  // ~100MB needed

    detect_kernel<<<1,64,0,stream>>>((const unsigned short*)d_in[0],flag);
    cvtT_kernel<<<SBn,256,0,stream>>>(b1,d_in[0],flag);
    prep_w1t<1><<<64,256,0,stream>>>(wqT,d_in[1],flag);
    cvt_kernel<<<1,128,0,stream>>>(bqf,d_in[2],128,flag);
    prep_w1t<1><<<64,256,0,stream>>>(wkT,d_in[3],flag);
    cvt_kernel<<<1,128,0,stream>>>(bkf,d_in[4],128,flag);
    prep_w1t<1><<<64,256,0,stream>>>(wvT,d_in[5],flag);
    cvt_kernel<<<1,128,0,stream>>>(bvf,d_in[6],128,flag);
    cvt_kernel<<<1,64,0,stream>>>(alphaf,d_in[7],1,flag);
    prep_msg_kernel<<<C_,C_,0,stream>>>(W2f,b2l,b2r,d_in[10],d_in[8],d_in[9],flag);
    prep_w1t<0><<<64,256,0,stream>>>(w2T,W2f,flag);
    cvt_kernel<<<1,64,0,stream>>>(weightf,d_in[11],1,flag);
    prep_wgt<<<64,256,0,stream>>>(wgTf,bgf2,d_in[12],d_in[13],flag);
    prep_w3t32<<<(256*2304+255)/256,256,0,stream>>>(wzrT,d_in[14],flag,256);
    cvt_kernel<<<1,256,0,stream>>>(bzrf,d_in[15],256,flag);
    prep_w3t32<<<(128*2304+255)/256,256,0,stream>>>(whT,d_in[16],flag,128);
    cvt_kernel<<<1,128,0,stream>>>(bhf,d_in[17],128,flag);
    prep_gbt<<<(CP_+255)/256,256,0,stream>>>(gamT,betT,d_in[18],d_in[19],flag);

    for(int it=0; it<3; ++it){
        // comb(b2) = w*(alpha*attn(h)+h) + (1-w)*(msgL+msgR)
        attn_all<<<SBn,512,0,stream>>>(b2,b1,wqT,wkT,wvT,bqf,bkf,bvf,
                                       w2T,b2l,b2r,wgTf,bgf2,alphaf,weightf);
        // GRU: zr([comb|h]) -> Z->b4 (y=0), RH->b3 (y=1), 32x32x16 MFMA
        conv3_zr<<<dim3(SBn,2),512,0,stream>>>(b4,b3,b2,b1,wzrT,bzrf,b1);
        // hhat([comb|RH]) + GRU combine + LN -> new hT (b1)
        conv3_hh<<<SBn,512,0,stream>>>(b1,b2,b3,whT,bhf,b4,b1,gamT,betT);
    }
    finalT_kernel<<<SBn,256,0,stream>>>(d_out,b1,flag);
}